// Round 3
// baseline (248.790 us; speedup 1.0000x reference)
//
#include <hip/hip_runtime.h>
#include <hip/hip_bf16.h>

// Problem: out[32768,128] = sigmoid(x[32768,1024] @ W[1024,128] + b[128]), all fp32.
// R7: barrier-free, LDS-free. W (256 KB bf16, swizzled to B-frag order) is
//     L2-resident and broadcast-read; staging it to LDS cost 3 barriers/phase
//     of lockstep (R6 showed ~1.3 us/phase). Now each wave is a free-running
//     stream: A-frags from HBM (float4 pairs), B-frags straight from L2
//     (global_load_dwordx4, 1KB/instr coalesced, same frag order -> identical
//     arithmetic), MFMA. 2048 independent waves, zero sync, full 32-slice
//     unroll so the compiler software-pipelines loads to its VGPR budget.

typedef __bf16 bf16x8 __attribute__((ext_vector_type(8)));
typedef float  f32x4  __attribute__((ext_vector_type(4)));

#define DIM   1024
#define NT    128
#define BATCH 32768

// ---------------------------------------------------------------------------
// Prep: W[k][n] fp32 -> bf16 in B-fragment order (unchanged).
// wsW[ ((s*8 + c)*64 + lane)*8 + j ] = W[ s*32 + (lane>>4)*8 + j ][ c*16 + (lane&15) ]
// ---------------------------------------------------------------------------
__global__ __launch_bounds__(256) void prep_w(const float* __restrict__ W,
                                              __bf16* __restrict__ wsW) {
    int idx = blockIdx.x * 256 + threadIdx.x;   // 0 .. 131071
    int j = idx & 7;
    int l = (idx >> 3) & 63;
    int c = (idx >> 9) & 7;
    int s = idx >> 12;
    int k = s * 32 + (l >> 4) * 8 + j;
    int n = c * 16 + (l & 15);
    wsW[idx] = (__bf16)W[k * NT + n];
}

__device__ __forceinline__ bf16x8 cvt_bf16x8(float4 a0, float4 a1) {
    bf16x8 af;
    af[0] = (__bf16)a0.x; af[1] = (__bf16)a0.y;
    af[2] = (__bf16)a0.z; af[3] = (__bf16)a0.w;
    af[4] = (__bf16)a1.x; af[5] = (__bf16)a1.y;
    af[6] = (__bf16)a1.z; af[7] = (__bf16)a1.w;
    return af;
}

// ---------------------------------------------------------------------------
// Main: block = 256 threads = 4 waves; wave tile 16 rows x 128 cols.
// Grid = 512 blocks (2048 waves; co-resident at <=256 VGPR). No LDS, no
// barriers. Per k-slice (K=32): 1 A-frag from HBM, 8 B-frags from L2, 8 MFMA.
// A-frag (16x16x32): lane holds A[m = lane&15][k = (lane>>4)*8 + j]
// B-frag:            lane holds B[k = (lane>>4)*8 + j][n = lane&15]
// C/D:               col = lane&15, row = (lane>>4)*4 + reg
// ---------------------------------------------------------------------------
__global__ __launch_bounds__(256, 2) void gemm_bias_sigmoid(
        const float* __restrict__ x,
        const __hip_bfloat16* __restrict__ wsWh,
        const float* __restrict__ bias,
        float* __restrict__ out) {
    const bf16x8* __restrict__ wsW8 = (const bf16x8*)wsWh;  // frag units of 16B

    const int tid  = threadIdx.x;
    const int lane = tid & 63;
    const int wave = tid >> 6;
    const int q    = lane >> 4;
    const int r    = lane & 15;
    const int row0 = blockIdx.x * 64 + wave * 16;

    const float*  xA  = x + (size_t)(row0 + r) * DIM + q * 8;
    const bf16x8* gB  = wsW8 + lane;    // frag f: gB[f * 64]

    f32x4 acc[8];
#pragma unroll
    for (int c = 0; c < 8; ++c)
        acc[c] = (f32x4){0.f, 0.f, 0.f, 0.f};

    // 32 k-slices, fully unrolled: compiler hoists/pipelines the independent
    // A (HBM) and B (L2) loads to its register budget. Same slice and frag
    // order as R4/R5 -> bit-identical accumulation.
#pragma unroll
    for (int s = 0; s < 32; ++s) {
        const float* ap = xA + (size_t)s * 32;
        const float4 a0 = *(const float4*)ap;
        const float4 a1 = *(const float4*)(ap + 4);
        const bf16x8 af = cvt_bf16x8(a0, a1);
#pragma unroll
        for (int c = 0; c < 8; ++c) {
            const bf16x8 bf = gB[(s * 8 + c) * 64];
            acc[c] = __builtin_amdgcn_mfma_f32_16x16x32_bf16(af, bf, acc[c], 0, 0, 0);
        }
    }

    // ---- epilogue: bias + sigmoid + store ----
#pragma unroll
    for (int c = 0; c < 8; ++c) {
        const float bv = bias[c * 16 + r];
#pragma unroll
        for (int reg = 0; reg < 4; ++reg) {
            const int row = row0 + q * 4 + reg;
            float v = acc[c][reg] + bv;
            v = 1.0f / (1.0f + __expf(-v));
            out[(size_t)row * NT + c * 16 + r] = v;
        }
    }
}

extern "C" void kernel_launch(void* const* d_in, const int* in_sizes, int n_in,
                              void* d_out, int out_size, void* d_ws, size_t ws_size,
                              hipStream_t stream) {
    const float* x = (const float*)d_in[0];   // [32768,1024]
    const float* W = (const float*)d_in[1];   // [1024,128]
    const float* b = (const float*)d_in[2];   // [128]
    float* out     = (float*)d_out;           // [32768,128]
    __bf16* wsW    = (__bf16*)d_ws;           // 256 KB swizzled bf16 W

    prep_w<<<DIM * NT / 256, 256, 0, stream>>>(W, wsW);
    gemm_bias_sigmoid<<<BATCH / 64, 256, 0, stream>>>(
        x, (const __hip_bfloat16*)wsW, b, out);
}

// Round 5
// 229.487 us; speedup vs baseline: 1.0841x; 1.0841x over previous
//
#include <hip/hip_runtime.h>
#include <hip/hip_bf16.h>

// Problem: out[32768,128] = sigmoid(x[32768,1024] @ W[1024,128] + b[128]), all fp32.
// R8b: stage-once + barrier-free (R8 de-risked: 64 KB LDS, 512-thr blocks).
//     Block = 8 waves owns 128 rows x 32 cols; W-slice (64 KB bf16, frag
//     order) staged to LDS ONCE via global_load_lds + one __syncthreads.
//     Main loop: ZERO barriers; per k-slice {depth-3 named A-prefetch from
//     HBM, 2x ds_read_b128, 2 MFMA}. 2 blocks/CU -> 16 waves/CU (2x R4/R5).
//     The 4 col-blocks of each row-group are adjacent on the SAME XCD
//     (bijective swizzle) so A re-reads hit that XCD's L2 (A HBM stays 134MB).

typedef __bf16 bf16x8 __attribute__((ext_vector_type(8)));
typedef float  f32x4  __attribute__((ext_vector_type(4)));

#define DIM   1024
#define NT    128
#define BATCH 32768

// ---------------------------------------------------------------------------
// Prep: W[k][n] fp32 -> bf16 in B-fragment order (unchanged).
// wsW[ ((s*8 + c)*64 + lane)*8 + j ] = W[ s*32 + (lane>>4)*8 + j ][ c*16 + (lane&15) ]
// ---------------------------------------------------------------------------
__global__ __launch_bounds__(256) void prep_w(const float* __restrict__ W,
                                              __bf16* __restrict__ wsW) {
    int idx = blockIdx.x * 256 + threadIdx.x;   // 0 .. 131071
    int j = idx & 7;
    int l = (idx >> 3) & 63;
    int c = (idx >> 9) & 7;
    int s = idx >> 12;
    int k = s * 32 + (l >> 4) * 8 + j;
    int n = c * 16 + (l & 15);
    wsW[idx] = (__bf16)W[k * NT + n];
}

__device__ __forceinline__ bf16x8 cvt_bf16x8(float4 a0, float4 a1) {
    bf16x8 af;
    af[0] = (__bf16)a0.x; af[1] = (__bf16)a0.y;
    af[2] = (__bf16)a0.z; af[3] = (__bf16)a0.w;
    af[4] = (__bf16)a1.x; af[5] = (__bf16)a1.y;
    af[6] = (__bf16)a1.z; af[7] = (__bf16)a1.w;
    return af;
}

// ---------------------------------------------------------------------------
// Main: grid = 1024 blocks x 512 threads (8 waves). Block (t,h): rows
// [t*128, t*128+128) x cols [h*32, h*32+32). Wave = 16 rows x 32 cols,
// acc = 2 f32x4. LDS = 64 KB: ldsW[(s*2+c')*64 + lane] = wsW frag
// (s*8 + h*2 + c')*64 + lane, s = 0..31, c' = 0..1.
// A-frag (16x16x32): lane holds A[m = lane&15][k = (lane>>4)*8 + j]
// B-frag:            lane holds B[k = (lane>>4)*8 + j][n = lane&15]
// C/D:               col = lane&15, row = (lane>>4)*4 + reg
// ---------------------------------------------------------------------------
__global__ __launch_bounds__(512, 4) void gemm_bias_sigmoid(
        const float* __restrict__ x,
        const __hip_bfloat16* __restrict__ wsWh,
        const float* __restrict__ bias,
        float* __restrict__ out) {
    const bf16x8* __restrict__ wsW8 = (const bf16x8*)wsWh;  // frag units of 16B
    __shared__ bf16x8 ldsW[4096];                           // 64 KB

    const int tid  = threadIdx.x;
    const int lane = tid & 63;
    const int wave = tid >> 6;          // 0..7
    const int q    = lane >> 4;
    const int r    = lane & 15;

    // Bijective swizzle: per XCD (u&7), 32 row-groups x 4 col-groups; the 4
    // col-blocks of a row-group are adjacent within the XCD for A L2 reuse.
    const int u    = blockIdx.x;        // 0..1023
    const int xcd  = u & 7;
    const int jj   = u >> 3;            // 0..127
    const int t    = xcd * 32 + (jj >> 2);   // 0..255
    const int h    = jj & 3;            // col group 0..3
    const int wrow = t * 128 + wave * 16;

    const float* xA = x + (size_t)(wrow + r) * DIM + q * 8;

#define LOADA(B, S)                                                    \
    {                                                                  \
        const float* ap_ = xA + (size_t)(S) * 32;                      \
        Aa[B] = *(const float4*)ap_;                                   \
        Ab[B] = *(const float4*)(ap_ + 4);                             \
    }

    // ---- A prefetch depth-3 (6 HBM loads in flight per wave) ----
    float4 Aa[3], Ab[3];                // constant-indexed after full unroll
    LOADA(0, 0)
    LOADA(1, 1)
    LOADA(2, 2)

    // ---- one-time W-slice stage: wave stages chunks m = wave*8 .. +7 ----
#pragma unroll
    for (int i = 0; i < 8; ++i) {
        const int m  = wave * 8 + i;      // 0..63 (chunk = 64 frag units)
        const int s  = m >> 1;            // 0..31
        const int cp = m & 1;             // 0..1
        const bf16x8* gsrc = wsW8 + (size_t)(s * 8 + h * 2 + cp) * 64 + lane;
        __builtin_amdgcn_global_load_lds(
            (const __attribute__((address_space(1))) void*)gsrc,
            (__attribute__((address_space(3))) void*)&ldsW[m * 64],
            16, 0, 0);
    }
    __syncthreads();    // only barrier in the kernel

    f32x4 acc[2];
    acc[0] = (f32x4){0.f, 0.f, 0.f, 0.f};
    acc[1] = (f32x4){0.f, 0.f, 0.f, 0.f};

    // ---- barrier-free main loop: 32 k-slices, fully unrolled ----
#pragma unroll
    for (int s = 0; s < 32; ++s) {
        const int b = s % 3;
        const bf16x8 af = cvt_bf16x8(Aa[b], Ab[b]);
        if (s + 3 < 32) LOADA(b, s + 3)    // refill freed buffer, 3 ahead
        const bf16x8* bp = &ldsW[s * 128 + lane];
        acc[0] = __builtin_amdgcn_mfma_f32_16x16x32_bf16(af, bp[0],  acc[0], 0, 0, 0);
        acc[1] = __builtin_amdgcn_mfma_f32_16x16x32_bf16(af, bp[64], acc[1], 0, 0, 0);
    }
#undef LOADA

    // ---- epilogue: bias + sigmoid + store ----
#pragma unroll
    for (int c = 0; c < 2; ++c) {
        const float bv = bias[h * 32 + c * 16 + r];
#pragma unroll
        for (int reg = 0; reg < 4; ++reg) {
            const int row = wrow + q * 4 + reg;
            float v = acc[c][reg] + bv;
            v = 1.0f / (1.0f + __expf(-v));
            out[(size_t)row * NT + h * 32 + c * 16 + r] = v;
        }
    }
}

extern "C" void kernel_launch(void* const* d_in, const int* in_sizes, int n_in,
                              void* d_out, int out_size, void* d_ws, size_t ws_size,
                              hipStream_t stream) {
    const float* x = (const float*)d_in[0];   // [32768,1024]
    const float* W = (const float*)d_in[1];   // [1024,128]
    const float* b = (const float*)d_in[2];   // [128]
    float* out     = (float*)d_out;           // [32768,128]
    __bf16* wsW    = (__bf16*)d_ws;           // 256 KB swizzled bf16 W

    prep_w<<<DIM * NT / 256, 256, 0, stream>>>(W, wsW);
    gemm_bias_sigmoid<<<BATCH / 32, 512, 0, stream>>>(
        x, (const __hip_bfloat16*)wsW, b, out);
}

// Round 6
// 225.791 us; speedup vs baseline: 1.1019x; 1.0164x over previous
//
#include <hip/hip_runtime.h>
#include <hip/hip_bf16.h>

// Problem: out[32768,128] = sigmoid(x[32768,1024] @ W[1024,128] + b[128]), all fp32.
// R9: full-width + barrier-free + forced pipelining.
//     Lessons: R6 -> barriers cost ~1.3us/phase; R8b -> column-splitting
//     quadruples A traffic and hits the ~6 TB/s L3/fabric ceiling (87.5us);
//     R7 -> compiler refuses to pipeline L2 B-loads on its own (VGPR=36).
//     So: wave = 16 rows x 128 cols (A read ONCE, 134 MB from L3), B-frags
//     straight from L2 (512 MB spread over 8 XCD L2s, 34.5 TB/s aggregate),
//     ZERO barriers/LDS, and explicit 3-bank register rotation for A and B
//     with sched_barrier(0) pinning each slice's prefetch above its MFMAs.
//     2048 waves co-resident (8/CU, one generation). Accumulation order
//     identical to R4 -> absmax unchanged.

typedef __bf16 bf16x8 __attribute__((ext_vector_type(8)));
typedef float  f32x4  __attribute__((ext_vector_type(4)));

#define DIM   1024
#define NT    128
#define BATCH 32768

// ---------------------------------------------------------------------------
// Prep: W[k][n] fp32 -> bf16 in B-fragment order (unchanged).
// wsW[ ((s*8 + c)*64 + lane)*8 + j ] = W[ s*32 + (lane>>4)*8 + j ][ c*16 + (lane&15) ]
// ---------------------------------------------------------------------------
__global__ __launch_bounds__(256) void prep_w(const float* __restrict__ W,
                                              __bf16* __restrict__ wsW) {
    int idx = blockIdx.x * 256 + threadIdx.x;   // 0 .. 131071
    int j = idx & 7;
    int l = (idx >> 3) & 63;
    int c = (idx >> 9) & 7;
    int s = idx >> 12;
    int k = s * 32 + (l >> 4) * 8 + j;
    int n = c * 16 + (l & 15);
    wsW[idx] = (__bf16)W[k * NT + n];
}

__device__ __forceinline__ bf16x8 cvt_bf16x8(float4 a0, float4 a1) {
    bf16x8 af;
    af[0] = (__bf16)a0.x; af[1] = (__bf16)a0.y;
    af[2] = (__bf16)a0.z; af[3] = (__bf16)a0.w;
    af[4] = (__bf16)a1.x; af[5] = (__bf16)a1.y;
    af[6] = (__bf16)a1.z; af[7] = (__bf16)a1.w;
    return af;
}

// ---------------------------------------------------------------------------
// Main: grid = 512 blocks x 256 threads (4 waves); wave = 16 rows x 128 cols.
// No LDS, no barriers. Per k-slice s: {cvt A(s); prefetch B(s+2) (8x 1KB L2
// loads into bank (s+2)%3); prefetch A(s+3) (2 HBM/L3 loads into bank s%3);
// sched_barrier; 8 MFMA from B bank s%3}. Steady state: ~26 VMEM in flight
// per wave; B loads lead their use by 2 slices, A by 3.
// A-frag (16x16x32): lane holds A[m = lane&15][k = (lane>>4)*8 + j]
// B-frag:            lane holds B[k = (lane>>4)*8 + j][n = lane&15]
// C/D:               col = lane&15, row = (lane>>4)*4 + reg
// ---------------------------------------------------------------------------
__global__ __launch_bounds__(256, 2) void gemm_bias_sigmoid(
        const float* __restrict__ x,
        const __hip_bfloat16* __restrict__ wsWh,
        const float* __restrict__ bias,
        float* __restrict__ out) {
    const bf16x8* __restrict__ wsW8 = (const bf16x8*)wsWh;  // frag units of 16B

    const int tid  = threadIdx.x;
    const int lane = tid & 63;
    const int wave = tid >> 6;
    const int q    = lane >> 4;
    const int r    = lane & 15;
    const int row0 = blockIdx.x * 64 + wave * 16;

    const float*  xA = x + (size_t)(row0 + r) * DIM + q * 8;
    const bf16x8* gB = wsW8 + lane;     // frag f at gB[f * 64]

    f32x4 acc[8];
#pragma unroll
    for (int c = 0; c < 8; ++c)
        acc[c] = (f32x4){0.f, 0.f, 0.f, 0.f};

#define LOADA(B, S)                                                    \
    {                                                                  \
        const float* ap_ = xA + (size_t)(S) * 32;                      \
        Aa[B] = *(const float4*)ap_;                                   \
        Ab[B] = *(const float4*)(ap_ + 4);                             \
    }

    // 3-bank register rotation for both streams (constant-indexed under
    // full unroll -> registers, no scratch).
    float4 Aa[3], Ab[3];
    bf16x8 Bb[3][8];

    // ---- prologue: A for slices 0..2 (6 loads), B for slices 0..1 (16) ----
    LOADA(0, 0)
    LOADA(1, 1)
    LOADA(2, 2)
#pragma unroll
    for (int c = 0; c < 8; ++c) Bb[0][c] = gB[(0 * 8 + c) * 64];
#pragma unroll
    for (int c = 0; c < 8; ++c) Bb[1][c] = gB[(1 * 8 + c) * 64];

    // ---- barrier-free main loop: 32 k-slices, fully unrolled ----
#pragma unroll
    for (int s = 0; s < 32; ++s) {
        const int bk = s % 3;                    // bank for A(s) and B(s)
        const bf16x8 af = cvt_bf16x8(Aa[bk], Ab[bk]);
        if (s + 2 < 32) {                        // prefetch B(s+2)
            const int bn = (s + 2) % 3;
#pragma unroll
            for (int c = 0; c < 8; ++c)
                Bb[bn][c] = gB[((s + 2) * 8 + c) * 64];
        }
        if (s + 3 < 32) LOADA(bk, s + 3)         // prefetch A(s+3)
        __builtin_amdgcn_sched_barrier(0);       // loads stay ABOVE the MFMAs
#pragma unroll
        for (int c = 0; c < 8; ++c)
            acc[c] = __builtin_amdgcn_mfma_f32_16x16x32_bf16(af, Bb[bk][c],
                                                             acc[c], 0, 0, 0);
    }
#undef LOADA

    // ---- epilogue: bias + sigmoid + store ----
#pragma unroll
    for (int c = 0; c < 8; ++c) {
        const float bv = bias[c * 16 + r];
#pragma unroll
        for (int reg = 0; reg < 4; ++reg) {
            const int row = row0 + q * 4 + reg;
            float v = acc[c][reg] + bv;
            v = 1.0f / (1.0f + __expf(-v));
            out[(size_t)row * NT + c * 16 + r] = v;
        }
    }
}

extern "C" void kernel_launch(void* const* d_in, const int* in_sizes, int n_in,
                              void* d_out, int out_size, void* d_ws, size_t ws_size,
                              hipStream_t stream) {
    const float* x = (const float*)d_in[0];   // [32768,1024]
    const float* W = (const float*)d_in[1];   // [1024,128]
    const float* b = (const float*)d_in[2];   // [128]
    float* out     = (float*)d_out;           // [32768,128]
    __bf16* wsW    = (__bf16*)d_ws;           // 256 KB swizzled bf16 W

    prep_w<<<DIM * NT / 256, 256, 0, stream>>>(W, wsW);
    gemm_bias_sigmoid<<<BATCH / 64, 256, 0, stream>>>(
        x, (const __hip_bfloat16*)wsW, b, out);
}

// Round 7
// 212.963 us; speedup vs baseline: 1.1682x; 1.0602x over previous
//
#include <hip/hip_runtime.h>
#include <hip/hip_bf16.h>

// Problem: out[32768,128] = sigmoid(x[32768,1024] @ W[1024,128] + b[128]), all fp32.
// R10: R9's schedule, but enforced with inline asm so the compiler cannot
//      delete it. R9 came back VGPR=44: the 3-bank rotation was folded away
//      and every B-load re-sunk to its MFMA (sched_barrier only guards the
//      scheduler, not sinking). Here every load is asm volatile
//      global_load_dwordx4 (mutually ordered), every wait a literal counted
//      s_waitcnt vmcnt(N) + sched_barrier(0) (rule #18). Steady state: ~28
//      loads in flight/wave, B leads use by 2 slices, A by 3; vmcnt(20) in
//      the loop, 0 only at slice 31. Wave = 16 rows x 128 cols (A read once),
//      B broadcast from L2, no LDS, no barriers. Same accumulation order.

typedef __bf16 bf16x8 __attribute__((ext_vector_type(8)));
typedef float  f32x4  __attribute__((ext_vector_type(4)));

#define DIM   1024
#define NT    128
#define BATCH 32768

// ---------------------------------------------------------------------------
// Prep: W[k][n] fp32 -> bf16 in B-fragment order (unchanged).
// wsW[ ((s*8 + c)*64 + lane)*8 + j ] = W[ s*32 + (lane>>4)*8 + j ][ c*16 + (lane&15) ]
// ---------------------------------------------------------------------------
__global__ __launch_bounds__(256) void prep_w(const float* __restrict__ W,
                                              __bf16* __restrict__ wsW) {
    int idx = blockIdx.x * 256 + threadIdx.x;   // 0 .. 131071
    int j = idx & 7;
    int l = (idx >> 3) & 63;
    int c = (idx >> 9) & 7;
    int s = idx >> 12;
    int k = s * 32 + (l >> 4) * 8 + j;
    int n = c * 16 + (l & 15);
    wsW[idx] = (__bf16)W[k * NT + n];
}

__device__ __forceinline__ bf16x8 cvt_bf16x8(float4 a0, float4 a1) {
    bf16x8 af;
    af[0] = (__bf16)a0.x; af[1] = (__bf16)a0.y;
    af[2] = (__bf16)a0.z; af[3] = (__bf16)a0.w;
    af[4] = (__bf16)a1.x; af[5] = (__bf16)a1.y;
    af[6] = (__bf16)a1.z; af[7] = (__bf16)a1.w;
    return af;
}

// counted wait + fence against MFMA hoisting (rule #18)
#define WVM2(n) asm volatile("s_waitcnt vmcnt(" #n ")" ::: "memory")
#define WVM(n)  do { WVM2(n); __builtin_amdgcn_sched_barrier(0); } while (0)

// ---- asm-pinned load primitives (volatile => program order preserved) ----
template<int BK, int S>
__device__ __forceinline__ void issueB(bf16x8 (&Bb)[3][8], const bf16x8* gB) {
#pragma unroll
    for (int c = 0; c < 8; ++c)
        asm volatile("global_load_dwordx4 %0, %1, off"
                     : "=v"(Bb[BK][c]) : "v"(gB + (S * 8 + c) * 64));
}

template<int BK, int S>
__device__ __forceinline__ void issueA(float4 (&Aa)[3], float4 (&Ab)[3],
                                       const float* xA) {
    asm volatile("global_load_dwordx4 %0, %1, off"
                 : "=v"(Aa[BK]) : "v"(xA + S * 32));
    asm volatile("global_load_dwordx4 %0, %1, off"
                 : "=v"(Ab[BK]) : "v"(xA + S * 32 + 4));
}

template<int BK>
__device__ __forceinline__ bf16x8 cvtA(float4 (&Aa)[3], float4 (&Ab)[3]) {
    return cvt_bf16x8(Aa[BK], Ab[BK]);
}

template<int BK>
__device__ __forceinline__ void mfma8(bf16x8 af, bf16x8 (&Bb)[3][8],
                                      f32x4 (&acc)[8]) {
#pragma unroll
    for (int c = 0; c < 8; ++c)
        acc[c] = __builtin_amdgcn_mfma_f32_16x16x32_bf16(af, Bb[BK][c],
                                                         acc[c], 0, 0, 0);
}

// ---------------------------------------------------------------------------
// Main: grid = 512 x 256 (4 waves); wave = 16 rows x 128 cols. No LDS, no
// barriers. Per step s: issue B(s+2) -> wait vmcnt (A(s),B(s) arrived, rest
// in flight) -> cvt A(s) -> issue A(s+3) into freed bank -> 8 MFMA.
// A-frag (16x16x32): lane holds A[m = lane&15][k = (lane>>4)*8 + j]
// B-frag:            lane holds B[k = (lane>>4)*8 + j][n = lane&15]
// C/D:               col = lane&15, row = (lane>>4)*4 + reg
// ---------------------------------------------------------------------------
__global__ __launch_bounds__(256, 2) void gemm_bias_sigmoid(
        const float* __restrict__ x,
        const __hip_bfloat16* __restrict__ wsWh,
        const float* __restrict__ bias,
        float* __restrict__ out) {
    const bf16x8* __restrict__ wsW8 = (const bf16x8*)wsWh;  // frag units of 16B

    const int tid  = threadIdx.x;
    const int lane = tid & 63;
    const int wave = tid >> 6;
    const int q    = lane >> 4;
    const int r    = lane & 15;
    const int row0 = blockIdx.x * 64 + wave * 16;

    const float*  xA = x + (size_t)(row0 + r) * DIM + q * 8;
    const bf16x8* gB = wsW8 + lane;     // frag f at gB[f * 64]

    f32x4 acc[8];
#pragma unroll
    for (int c = 0; c < 8; ++c)
        acc[c] = (f32x4){0.f, 0.f, 0.f, 0.f};

    float4 Aa[3], Ab[3];
    bf16x8 Bb[3][8];

    // ---- prologue: 22 loads in flight ----
    issueA<0, 0>(Aa, Ab, xA);
    issueA<1, 1>(Aa, Ab, xA);
    issueA<2, 2>(Aa, Ab, xA);
    issueB<0, 0>(Bb, gB);
    issueB<1, 1>(Bb, gB);

#define ST(BN, SB, WN, BA, SA)                                        \
    { issueB<BN, SB>(Bb, gB); WVM(WN);                                \
      bf16x8 af = cvtA<BA>(Aa, Ab); issueA<BA, SA>(Aa, Ab, xA);       \
      mfma8<BA>(af, Bb, acc); }
#define STNA(BN, SB, WN, BA)                                          \
    { issueB<BN, SB>(Bb, gB); WVM(WN);                                \
      bf16x8 af = cvtA<BA>(Aa, Ab); mfma8<BA>(af, Bb, acc); }
#define STNB(WN, BA)                                                  \
    { WVM(WN); bf16x8 af = cvtA<BA>(Aa, Ab); mfma8<BA>(af, Bb, acc); }

    ST(2,  2, 16, 0,  3)   // s=0
    ST(0,  3, 18, 1,  4)   // s=1
    ST(1,  4, 20, 2,  5)   // s=2
    ST(2,  5, 20, 0,  6)   // s=3
    ST(0,  6, 20, 1,  7)   // s=4
    ST(1,  7, 20, 2,  8)   // s=5
    ST(2,  8, 20, 0,  9)   // s=6
    ST(0,  9, 20, 1, 10)   // s=7
    ST(1, 10, 20, 2, 11)   // s=8
    ST(2, 11, 20, 0, 12)   // s=9
    ST(0, 12, 20, 1, 13)   // s=10
    ST(1, 13, 20, 2, 14)   // s=11
    ST(2, 14, 20, 0, 15)   // s=12
    ST(0, 15, 20, 1, 16)   // s=13
    ST(1, 16, 20, 2, 17)   // s=14
    ST(2, 17, 20, 0, 18)   // s=15
    ST(0, 18, 20, 1, 19)   // s=16
    ST(1, 19, 20, 2, 20)   // s=17
    ST(2, 20, 20, 0, 21)   // s=18
    ST(0, 21, 20, 1, 22)   // s=19
    ST(1, 22, 20, 2, 23)   // s=20
    ST(2, 23, 20, 0, 24)   // s=21
    ST(0, 24, 20, 1, 25)   // s=22
    ST(1, 25, 20, 2, 26)   // s=23
    ST(2, 26, 20, 0, 27)   // s=24
    ST(0, 27, 20, 1, 28)   // s=25
    ST(1, 28, 20, 2, 29)   // s=26
    ST(2, 29, 20, 0, 30)   // s=27
    ST(0, 30, 20, 1, 31)   // s=28
    STNA(1, 31, 20, 2)     // s=29
    STNB(10, 0)            // s=30
    STNB(0, 1)             // s=31
#undef ST
#undef STNA
#undef STNB

    // ---- epilogue: bias + sigmoid + store ----
#pragma unroll
    for (int c = 0; c < 8; ++c) {
        const float bv = bias[c * 16 + r];
#pragma unroll
        for (int reg = 0; reg < 4; ++reg) {
            const int row = row0 + q * 4 + reg;
            float v = acc[c][reg] + bv;
            v = 1.0f / (1.0f + __expf(-v));
            out[(size_t)row * NT + c * 16 + r] = v;
        }
    }
}

extern "C" void kernel_launch(void* const* d_in, const int* in_sizes, int n_in,
                              void* d_out, int out_size, void* d_ws, size_t ws_size,
                              hipStream_t stream) {
    const float* x = (const float*)d_in[0];   // [32768,1024]
    const float* W = (const float*)d_in[1];   // [1024,128]
    const float* b = (const float*)d_in[2];   // [128]
    float* out     = (float*)d_out;           // [32768,128]
    __bf16* wsW    = (__bf16*)d_ws;           // 256 KB swizzled bf16 W

    prep_w<<<DIM * NT / 256, 256, 0, stream>>>(W, wsW);
    gemm_bias_sigmoid<<<BATCH / 64, 256, 0, stream>>>(
        x, (const __hip_bfloat16*)wsW, b, out);
}

// Round 8
// 211.315 us; speedup vs baseline: 1.1773x; 1.0078x over previous
//
#include <hip/hip_runtime.h>
#include <hip/hip_bf16.h>

// Problem: out[32768,128] = sigmoid(x[32768,1024] @ W[1024,128] + b[128]), all fp32.
// R11: R4's proven 4-phase LDS structure, blocks 2x taller to halve W-staging
//      traffic. Byte audit of R4/R5 (61.5us): A 134MB + W-stage 128MB (512
//      blocks x 256KB!) + out 17MB = 279MB ~ 4.6TB/s = ~73% of copy ceiling.
//      L2-direct B (R7/R9/R10) loses even perfectly scheduled (72us). So:
//      block = 512 thr / 8 waves / 128 rows, full 128-col width, grid = 256.
//      W-stage traffic halves to 64MB. A-prefetch = 3-bank x 2-slice rotation
//      (48 VGPR) -> fits <=128 VGPR -> 2 blocks/CU = 16 waves/CU (2x R4).
//      Same phase barriers, same k-accumulation order (absmax unchanged).

typedef __bf16 bf16x8 __attribute__((ext_vector_type(8)));
typedef float  f32x4  __attribute__((ext_vector_type(4)));

#define DIM   1024
#define NT    128
#define BATCH 32768

// ---------------------------------------------------------------------------
// Prep: W[k][n] fp32 -> bf16 in B-fragment order (unchanged).
// wsW[ ((s*8 + c)*64 + lane)*8 + j ] = W[ s*32 + (lane>>4)*8 + j ][ c*16 + (lane&15) ]
// ---------------------------------------------------------------------------
__global__ __launch_bounds__(256) void prep_w(const float* __restrict__ W,
                                              __bf16* __restrict__ wsW) {
    int idx = blockIdx.x * 256 + threadIdx.x;   // 0 .. 131071
    int j = idx & 7;
    int l = (idx >> 3) & 63;
    int c = (idx >> 9) & 7;
    int s = idx >> 12;
    int k = s * 32 + (l >> 4) * 8 + j;
    int n = c * 16 + (l & 15);
    wsW[idx] = (__bf16)W[k * NT + n];
}

__device__ __forceinline__ bf16x8 cvt_bf16x8(float4 a0, float4 a1) {
    bf16x8 af;
    af[0] = (__bf16)a0.x; af[1] = (__bf16)a0.y;
    af[2] = (__bf16)a0.z; af[3] = (__bf16)a0.w;
    af[4] = (__bf16)a1.x; af[5] = (__bf16)a1.y;
    af[6] = (__bf16)a1.z; af[7] = (__bf16)a1.w;
    return af;
}

// ---------------------------------------------------------------------------
// Main: grid = 256 blocks x 512 threads (8 waves); wave = 16 rows x 128 cols,
// block = 128 rows. LDS = 64 KB single buffer; per phase p (K=256): stage
// wsW8[p*4096 .. +4096) linearly via global_load_lds, then 8 k-slices of
// {1 A-frag, 8 B-frags from LDS, 8 MFMA}. A uses 3 banks (QA,QB,QC) of 2
// slices each; the one partially-exposed A-wait per phase is covered by
// 16 waves/CU. Phase rotation: (X,Y,Z) -> (Y,Z,X).
// A-frag (16x16x32): lane holds A[m = lane&15][k = (lane>>4)*8 + j]
// B-frag:            lane holds B[k = (lane>>4)*8 + j][n = lane&15]
// C/D:               col = lane&15, row = (lane>>4)*4 + reg
// ---------------------------------------------------------------------------
__global__ __launch_bounds__(512, 4) void gemm_bias_sigmoid(
        const float* __restrict__ x,
        const __hip_bfloat16* __restrict__ wsWh,
        const float* __restrict__ bias,
        float* __restrict__ out) {
    const bf16x8* __restrict__ wsW8 = (const bf16x8*)wsWh;  // frag units of 16B
    __shared__ bf16x8 ldsW[4096];                           // 64 KB

    const int tid  = threadIdx.x;
    const int lane = tid & 63;
    const int wave = tid >> 6;          // 0..7
    const int q    = lane >> 4;
    const int r    = lane & 15;
    const int row0 = blockIdx.x * 128 + wave * 16;

    const float* xA = x + (size_t)(row0 + r) * DIM + q * 8;

    f32x4 acc[8];
#pragma unroll
    for (int c = 0; c < 8; ++c)
        acc[c] = (f32x4){0.f, 0.f, 0.f, 0.f};

    // 3 A-banks, 2 k-slices each (4 float4 = 16 VGPR per bank).
    float4 QA[4], QB[4], QC[4];

#define LOADQ(Q, S)                                                     \
    {                                                                   \
        const float* ap_ = xA + (size_t)(S) * 32;                       \
        Q[0] = *(const float4*)ap_;  Q[1] = *(const float4*)(ap_ + 4);  \
        const float* aq_ = ap_ + 32;                                    \
        Q[2] = *(const float4*)aq_;  Q[3] = *(const float4*)(aq_ + 4);  \
    }

    // compute 2 k-slices (phase-local SL, SL+1) from bank Q
#define COMP2(Q, SL)                                                        \
    {                                                                       \
        const bf16x8 af0 = cvt_bf16x8(Q[0], Q[1]);                          \
        _Pragma("unroll")                                                   \
        for (int c = 0; c < 8; ++c)                                         \
            acc[c] = __builtin_amdgcn_mfma_f32_16x16x32_bf16(               \
                af0, ldsW[((SL) * 8 + c) * 64 + lane], acc[c], 0, 0, 0);    \
        const bf16x8 af1 = cvt_bf16x8(Q[2], Q[3]);                          \
        _Pragma("unroll")                                                   \
        for (int c = 0; c < 8; ++c)                                         \
            acc[c] = __builtin_amdgcn_mfma_f32_16x16x32_bf16(               \
                af1, ldsW[((SL) * 8 + 8 + c) * 64 + lane], acc[c], 0, 0, 0);\
    }

    // stage phase P: wave handles chunks m = wave*8 .. +7 (64 frag units ea.)
#define STAGE(P)                                                            \
    {                                                                       \
        _Pragma("unroll")                                                   \
        for (int i = 0; i < 8; ++i) {                                       \
            const int m = wave * 8 + i;                                     \
            const bf16x8* gsrc = wsW8 + (size_t)(P) * 4096 + m * 64 + lane; \
            __builtin_amdgcn_global_load_lds(                               \
                (const __attribute__((address_space(1))) void*)gsrc,        \
                (__attribute__((address_space(3))) void*)&ldsW[m * 64],     \
                16, 0, 0);                                                  \
        }                                                                   \
    }

    // One phase. Entry (after sync b): X = slices 8P,8P+1; Y = 8P+2,3;
    // Z = 8P+4,5 (all complete - syncthreads drains vmcnt). LAST skips
    // next-phase A loads.
#define PHASE(P, X, Y, Z, LAST)                                             \
    {                                                                       \
        __syncthreads();                /* (a) prior LDS reads done */      \
        STAGE(P)                                                            \
        LOADQ(Z, (P) * 8 + 4)           /* completes under barrier drain */ \
        __syncthreads();                /* (b) staging visible */           \
        COMP2(X, 0) LOADQ(X, (P) * 8 + 6)                                   \
        COMP2(Y, 2) if (!(LAST)) LOADQ(Y, (P) * 8 + 8)                      \
        COMP2(Z, 4) if (!(LAST)) LOADQ(Z, (P) * 8 + 10)                     \
        COMP2(X, 6)                                                         \
    }

    // prologue: A slices 0,1 and 2,3
    LOADQ(QA, 0)
    LOADQ(QB, 2)

    PHASE(0, QA, QB, QC, 0)   // after: QB=8,9  QC=10,11
    PHASE(1, QB, QC, QA, 0)   // after: QC=16,17 QA=18,19
    PHASE(2, QC, QA, QB, 0)   // after: QA=24,25 QB=26,27
    PHASE(3, QA, QB, QC, 1)

#undef PHASE
#undef STAGE
#undef COMP2
#undef LOADQ

    // ---- epilogue: bias + sigmoid + store ----
#pragma unroll
    for (int c = 0; c < 8; ++c) {
        const float bv = bias[c * 16 + r];
#pragma unroll
        for (int reg = 0; reg < 4; ++reg) {
            const int row = row0 + q * 4 + reg;
            float v = acc[c][reg] + bv;
            v = 1.0f / (1.0f + __expf(-v));
            out[(size_t)row * NT + c * 16 + r] = v;
        }
    }
}

extern "C" void kernel_launch(void* const* d_in, const int* in_sizes, int n_in,
                              void* d_out, int out_size, void* d_ws, size_t ws_size,
                              hipStream_t stream) {
    const float* x = (const float*)d_in[0];   // [32768,1024]
    const float* W = (const float*)d_in[1];   // [1024,128]
    const float* b = (const float*)d_in[2];   // [128]
    float* out     = (float*)d_out;           // [32768,128]
    __bf16* wsW    = (__bf16*)d_ws;           // 256 KB swizzled bf16 W

    prep_w<<<DIM * NT / 256, 256, 0, stream>>>(W, wsW);
    gemm_bias_sigmoid<<<BATCH / 128, 512, 0, stream>>>(
        x, (const __hip_bfloat16*)wsW, b, out);
}